// Round 2
// baseline (153.089 us; speedup 1.0000x reference)
//
#include <hip/hip_runtime.h>
#include <float.h>

// Tropical (max-plus) linear: y[b,o] = max_i (x[b,i] + W[o,i])
// B=512, I=1024, O=1024, fp32. No MFMA possible (max-plus semiring) -> fp32 VALU.
//
// Round-2 design:
//  * Pre-transpose x->xT[I][B] and W->wT[I][O] into d_ws (LDS tile transpose).
//  * Main kernel: 128x128 output tile, K-split 8 -> grid 8x4x8 = 256 blocks
//    (1/CU), 256 threads, 8x8 outputs/thread (fragments split 4+4 at +64 so
//    LDS b128 reads are <=2-way bank-aliased = free).
//  * Staging: __builtin_amdgcn_global_load_lds width 16 (no ds_writes, no
//    transpose VALU), double-buffered LDS, KT=32 chunks.
//  * Inner loop: k-pair unroll -> v_max3_f32 (1.5 VALU/MAC). Balanced LDS/VALU:
//    192 cyc/k each.
//  * K-split merge: float atomic-max via int-max (v>=0) / uint-min (v<0) on
//    y pre-initialized to 0xFFFFFFFF bytes (memsetAsync).

#define B_DIM 512
#define I_DIM 1024
#define O_DIM 1024

#define BT 128
#define OT 128
#define KSPLIT 8
#define KB (I_DIM / KSPLIT)   // 128 k per block
#define KT 32                 // k per staged chunk
#define NCH (KB / KT)         // 4 chunks

__device__ __forceinline__ void g2lds16(const float* g, float* l) {
    // async copy: 64 lanes x 16B; LDS dest = wave-uniform base + lane*16
    __builtin_amdgcn_global_load_lds(
        (const __attribute__((address_space(1))) void*)g,
        (__attribute__((address_space(3))) void*)l, 16, 0, 0);
}

__device__ __forceinline__ void atomicMaxFloat(float* addr, float v) {
    // Correct for all finite floats when *addr is initialized to 0xFFFFFFFF:
    // as int, 0xFFFFFFFF = -1 (loses int-max vs any v>=0);
    // as uint it is the max (loses uint-min vs any negative v).
    if (v >= 0.0f) atomicMax((int*)addr, __float_as_int(v));
    else           atomicMin((unsigned int*)addr, __float_as_uint(v));
}

__global__ __launch_bounds__(256, 1) void trop_main(
    const float* __restrict__ xT,   // [I_DIM][B_DIM]
    const float* __restrict__ wT,   // [I_DIM][O_DIM]
    float* __restrict__ y)          // [B_DIM][O_DIM]
{
    __shared__ float xs[2][KT * BT];   // 16 KB each buf
    __shared__ float ws[2][KT * OT];   // 16 KB each buf

    const int tid  = threadIdx.x;
    const int to   = tid & 15;     // o-fragment selector (0..15)
    const int tb   = tid >> 4;     // b-fragment selector (0..15)
    const int wave = tid >> 6;     // 0..3
    const int lane = tid & 63;
    const int o0    = blockIdx.x * OT;
    const int b0    = blockIdx.y * BT;
    const int kbase = blockIdx.z * KB;

    const int rsub = lane >> 5;          // 0/1: which of 2 rows in a 1KB chunk
    const int csub = (lane & 31) * 4;    // float col within row

    float acc[8][8];
    #pragma unroll
    for (int i = 0; i < 8; ++i)
        #pragma unroll
        for (int j = 0; j < 8; ++j)
            acc[i][j] = -FLT_MAX;

    // ---- stage chunk c into buffer buf (pure async DMA, no VGPR roundtrip)
    auto stage = [&](int c, int buf) {
        const int k0 = kbase + c * KT;
        #pragma unroll
        for (int i = 0; i < 4; ++i) {
            const int t   = wave * 4 + i;            // 0..15, wave-uniform
            const int row = k0 + 2 * t + rsub;       // per-lane k row
            g2lds16(&xT[row * B_DIM + b0 + csub], &xs[buf][t * 256]);
        }
        #pragma unroll
        for (int i = 0; i < 4; ++i) {
            const int t   = wave * 4 + i;
            const int row = k0 + 2 * t + rsub;
            g2lds16(&wT[row * O_DIM + o0 + csub], &ws[buf][t * 256]);
        }
    };

    auto compute = [&](int buf) {
        for (int k = 0; k < KT; k += 2) {
            // fragments split 4+4 at +64 floats: b128 addrs land on 8 distinct
            // bank-quads -> 2-way aliasing (free)
            float4 xa0 = *(const float4*)&xs[buf][k * BT + 4 * tb];
            float4 xa1 = *(const float4*)&xs[buf][k * BT + 64 + 4 * tb];
            float4 xb0 = *(const float4*)&xs[buf][(k + 1) * BT + 4 * tb];
            float4 xb1 = *(const float4*)&xs[buf][(k + 1) * BT + 64 + 4 * tb];
            float4 wa0 = *(const float4*)&ws[buf][k * OT + 4 * to];
            float4 wa1 = *(const float4*)&ws[buf][k * OT + 64 + 4 * to];
            float4 wb0 = *(const float4*)&ws[buf][(k + 1) * OT + 4 * to];
            float4 wb1 = *(const float4*)&ws[buf][(k + 1) * OT + 64 + 4 * to];

            const float xa[8] = {xa0.x, xa0.y, xa0.z, xa0.w, xa1.x, xa1.y, xa1.z, xa1.w};
            const float xb[8] = {xb0.x, xb0.y, xb0.z, xb0.w, xb1.x, xb1.y, xb1.z, xb1.w};
            const float wa[8] = {wa0.x, wa0.y, wa0.z, wa0.w, wa1.x, wa1.y, wa1.z, wa1.w};
            const float wb[8] = {wb0.x, wb0.y, wb0.z, wb0.w, wb1.x, wb1.y, wb1.z, wb1.w};

            #pragma unroll
            for (int i = 0; i < 8; ++i)
                #pragma unroll
                for (int j = 0; j < 8; ++j) {
                    const float s0 = xa[i] + wa[j];
                    const float s1 = xb[i] + wb[j];
                    // fmax(acc, fmax(s0,s1)) -> v_max3_f32
                    acc[i][j] = fmaxf(acc[i][j], fmaxf(s0, s1));
                }
        }
    };

    stage(0, 0);
    for (int c = 0; c < NCH; ++c) {
        __syncthreads();   // drains own vmcnt -> chunk c staged; prev compute done
        if (c + 1 < NCH) stage(c + 1, (c + 1) & 1);   // in flight under compute
        compute(c & 1);
    }

    // ---- epilogue: merge K-split partials via atomic float-max
    #pragma unroll
    for (int h = 0; h < 2; ++h)
        #pragma unroll
        for (int ii = 0; ii < 4; ++ii) {
            const int b = b0 + 64 * h + 4 * tb + ii;
            #pragma unroll
            for (int g = 0; g < 2; ++g)
                #pragma unroll
                for (int jj = 0; jj < 4; ++jj) {
                    const int o = o0 + 64 * g + 4 * to + jj;
                    atomicMaxFloat(&y[b * O_DIM + o], acc[4 * h + ii][4 * g + jj]);
                }
        }
}

// ---- 32x32 LDS tile transpose: out[c][r] = in[r][c]
__global__ __launch_bounds__(256) void transpose_k(
    const float* __restrict__ in, float* __restrict__ out, int R, int C)
{
    __shared__ float tile[32][33];
    const int tx = threadIdx.x;        // 0..31
    const int ty = threadIdx.y;        // 0..7
    const int r0 = blockIdx.y * 32;
    const int c0 = blockIdx.x * 32;
    #pragma unroll
    for (int i = 0; i < 4; ++i)
        tile[ty + 8 * i][tx] = in[(r0 + ty + 8 * i) * C + c0 + tx];
    __syncthreads();
    #pragma unroll
    for (int i = 0; i < 4; ++i)
        out[(c0 + ty + 8 * i) * R + r0 + tx] = tile[tx][ty + 8 * i];
}

extern "C" void kernel_launch(void* const* d_in, const int* in_sizes, int n_in,
                              void* d_out, int out_size, void* d_ws, size_t ws_size,
                              hipStream_t stream) {
    const float* x = (const float*)d_in[0];
    const float* W = (const float*)d_in[1];
    float* y  = (float*)d_out;
    float* xT = (float*)d_ws;                  // [I][B]  2 MB
    float* wT = xT + (size_t)B_DIM * I_DIM;    // [I][O]  4 MB

    transpose_k<<<dim3(I_DIM / 32, B_DIM / 32), dim3(32, 8), 0, stream>>>(x, xT, B_DIM, I_DIM);
    transpose_k<<<dim3(I_DIM / 32, O_DIM / 32), dim3(32, 8), 0, stream>>>(W, wT, O_DIM, I_DIM);

    // init y to 0xFFFFFFFF (required by atomicMaxFloat's int/uint trick)
    hipMemsetAsync(d_out, 0xFF, (size_t)B_DIM * O_DIM * sizeof(float), stream);

    trop_main<<<dim3(O_DIM / OT, B_DIM / BT, KSPLIT), dim3(256), 0, stream>>>(xT, wT, y);
}

// Round 3
// 99.057 us; speedup vs baseline: 1.5455x; 1.5455x over previous
//
#include <hip/hip_runtime.h>
#include <float.h>

// Tropical (max-plus) linear: y[b,o] = max_i (x[b,i] + W[o,i])
// B=512, I=1024, O=1024, fp32. No MFMA (max-plus semiring) -> fp32 VALU.
//
// Round-3 design:
//  * 128x128 output tile, K-split (default 8) -> 8x4x8 = 256 blocks (1/CU),
//    256 threads, 8x8 outputs/thread (balanced: LDS b128 cyc == VALU cyc).
//  * NO pre-transpose: stage row-major tiles via global_load_lds width 16.
//    Each lane picks its global 16B; k-quads XOR-swizzled (q = c ^ (row&7))
//    at 16B granularity so compute-side b128 reads are conflict-free.
//  * Fragment rows = t + 16*frag  ->  swizzle is per-thread-uniform.
//  * Inner loop: k-pair max3 (1.5 VALU op / MAC; 10.2 us VALU floor).
//  * NO atomics: K-split partials to private slabs in d_ws; reduce kernel
//    does y = max over slabs.  (Round-2 atomics cost ~80 us.)

#define B_DIM 512
#define I_DIM 1024
#define O_DIM 1024
#define BT 128
#define OT 128
#define KT 32            // k per staged chunk

static_assert(sizeof(float4) == 16, "");

__device__ __forceinline__ void g2lds16(const float* g, float* l) {
    __builtin_amdgcn_global_load_lds(
        (const __attribute__((address_space(1))) void*)g,
        (__attribute__((address_space(3))) void*)l, 16, 0, 0);
}

template <int KB>   // k per block = I_DIM / KSPLIT
__global__ __launch_bounds__(256, 1) void trop_main(
    const float* __restrict__ x,    // [B_DIM][I_DIM]
    const float* __restrict__ W,    // [O_DIM][I_DIM]
    float* __restrict__ part)       // [KSPLIT][B_DIM][O_DIM]
{
    constexpr int NCH = KB / KT;
    __shared__ float xs[2][BT * KT];   // 16 KB per buf, [row][k] 16B-swizzled
    __shared__ float ws[2][OT * KT];

    const int tid  = threadIdx.x;
    const int to   = tid & 15;      // o-fragment selector (0..15)
    const int tb   = tid >> 4;      // b-fragment selector (0..15)
    const int wave = tid >> 6;
    const int lane = tid & 63;
    const int o0 = blockIdx.x * OT;
    const int b0 = blockIdx.y * BT;
    const int kz = blockIdx.z;
    const int kbase = kz * KB;

    // staging lane geometry: each 1KB instr covers 8 rows x 8 swizzled k-quads
    const int ro8 = lane >> 3;                 // row within 8-row group
    const int q   = (lane & 7) ^ ro8;          // global k-quad for this LDS slot

    float acc[8][8];
    #pragma unroll
    for (int i = 0; i < 8; ++i)
        #pragma unroll
        for (int j = 0; j < 8; ++j)
            acc[i][j] = -FLT_MAX;

    auto stage = [&](int c, int buf) {
        const int k0 = kbase + c * KT;
        #pragma unroll
        for (int i = 0; i < 4; ++i) {
            const int t = wave * 4 + i;                     // 0..15 (8-row group)
            g2lds16(&x[(size_t)(b0 + 8 * t + ro8) * I_DIM + k0 + 4 * q],
                    &xs[buf][t * 256]);
        }
        #pragma unroll
        for (int i = 0; i < 4; ++i) {
            const int t = wave * 4 + i;
            g2lds16(&W[(size_t)(o0 + 8 * t + ro8) * I_DIM + k0 + 4 * q],
                    &ws[buf][t * 256]);
        }
    };

    const int swx = tb & 7;   // per-thread k-quad swizzle (x rows: tb+16*ii)
    const int swo = to & 7;   // (W rows: to+16*jj)

    auto compute = [&](int buf) {
        #pragma unroll 2
        for (int kq = 0; kq < KT / 4; ++kq) {
            float4 xv[8], wv[8];
            #pragma unroll
            for (int ii = 0; ii < 8; ++ii)
                xv[ii] = *(const float4*)&xs[buf][(tb + 16 * ii) * KT + 4 * (kq ^ swx)];
            #pragma unroll
            for (int jj = 0; jj < 8; ++jj)
                wv[jj] = *(const float4*)&ws[buf][(to + 16 * jj) * KT + 4 * (kq ^ swo)];
            #pragma unroll
            for (int ii = 0; ii < 8; ++ii)
                #pragma unroll
                for (int jj = 0; jj < 8; ++jj) {
                    const float s0 = xv[ii].x + wv[jj].x;
                    const float s1 = xv[ii].y + wv[jj].y;
                    acc[ii][jj] = fmaxf(acc[ii][jj], fmaxf(s0, s1));  // v_max3
                    const float s2 = xv[ii].z + wv[jj].z;
                    const float s3 = xv[ii].w + wv[jj].w;
                    acc[ii][jj] = fmaxf(acc[ii][jj], fmaxf(s2, s3));
                }
        }
    };

    stage(0, 0);
    for (int c = 0; c < NCH; ++c) {
        __syncthreads();                       // chunk c staged; prev LDS reads done
        if (c + 1 < NCH) stage(c + 1, (c + 1) & 1);   // DMA overlaps compute
        compute(c & 1);
    }

    // epilogue: private slab, plain coalesced stores (16 consecutive floats/quarter-wave)
    float* pout = part + (size_t)kz * (B_DIM * O_DIM);
    #pragma unroll
    for (int ii = 0; ii < 8; ++ii) {
        const int b = b0 + tb + 16 * ii;
        #pragma unroll
        for (int jj = 0; jj < 8; ++jj)
            pout[(size_t)b * O_DIM + o0 + to + 16 * jj] = acc[ii][jj];
    }
}

template <int KS>
__global__ __launch_bounds__(256) void trop_reduce(
    const float* __restrict__ part, float* __restrict__ y)
{
    constexpr int N4 = B_DIM * O_DIM / 4;
    const int idx = blockIdx.x * 256 + threadIdx.x;
    const float4* p = (const float4*)part;
    float4 m = p[idx];
    #pragma unroll
    for (int s = 1; s < KS; ++s) {
        const float4 v = p[(size_t)s * N4 + idx];
        m.x = fmaxf(m.x, v.x); m.y = fmaxf(m.y, v.y);
        m.z = fmaxf(m.z, v.z); m.w = fmaxf(m.w, v.w);
    }
    ((float4*)y)[idx] = m;
}

extern "C" void kernel_launch(void* const* d_in, const int* in_sizes, int n_in,
                              void* d_out, int out_size, void* d_ws, size_t ws_size,
                              hipStream_t stream) {
    const float* x = (const float*)d_in[0];
    const float* W = (const float*)d_in[1];
    float* y = (float*)d_out;
    float* part = (float*)d_ws;
    const size_t slab = (size_t)B_DIM * O_DIM * sizeof(float);   // 2 MB

    if (ws_size >= 8 * slab) {
        trop_main<I_DIM / 8><<<dim3(O_DIM / OT, B_DIM / BT, 8), 256, 0, stream>>>(x, W, part);
        trop_reduce<8><<<dim3(B_DIM * O_DIM / 4 / 256), 256, 0, stream>>>(part, y);
    } else if (ws_size >= 4 * slab) {
        trop_main<I_DIM / 4><<<dim3(O_DIM / OT, B_DIM / BT, 4), 256, 0, stream>>>(x, W, part);
        trop_reduce<4><<<dim3(B_DIM * O_DIM / 4 / 256), 256, 0, stream>>>(part, y);
    } else if (ws_size >= 2 * slab) {
        trop_main<I_DIM / 2><<<dim3(O_DIM / OT, B_DIM / BT, 2), 256, 0, stream>>>(x, W, part);
        trop_reduce<2><<<dim3(B_DIM * O_DIM / 4 / 256), 256, 0, stream>>>(part, y);
    } else {
        // no workspace: single block-column does full K, writes y directly
        trop_main<I_DIM><<<dim3(O_DIM / OT, B_DIM / BT, 1), 256, 0, stream>>>(x, W, y);
    }
}

// Round 4
// 91.155 us; speedup vs baseline: 1.6794x; 1.0867x over previous
//
#include <hip/hip_runtime.h>
#include <float.h>

// Tropical (max-plus) linear: y[b,o] = max_i (x[b,i] + W[o,i])
// B=512, I=1024, O=1024, fp32. No MFMA (max-plus semiring) -> fp32 VALU.
//
// Round-4: same tiling/swizzle as round 3 (verified correct, conflict-free),
// but the inner loop is an explicit software pipeline sized to FIT in VGPRs:
//   - x fragments: 2 parity banks x 8 float4 (cross-kq prefetch)   64 regs
//   - W fragments: 2-deep rotating buffer (prefetch depth 2 in jj)  8 regs
//   - acc 8x8                                                      64 regs
//   Round-3's "hold all 16 frags" needed ~200 regs; compiler gave 88 and
//   silently reloaded W per use -> 4.5x LDS-pipe inflation (48.7 us ~= 4.5 x
//   the 10.2 us balanced floor). This version needs ~150.
// Packed math: fragments are ext_vector float4; xv + wv -> v_pk_add_f32
//   (2 instrs), then 2x v_max3_f32 -> 4 VALU / output / k-quad.
// Occupancy: KSPLIT=16 -> 512 blocks = 2 blocks/CU (LDS 64 KB/block), with
//   __launch_bounds__(256,2). Partial slabs in d_ws, max-reduce at the end.

#define B_DIM 512
#define I_DIM 1024
#define O_DIM 1024
#define BT 128
#define OT 128
#define KT 32            // k per staged chunk

typedef float f32x4 __attribute__((ext_vector_type(4)));

__device__ __forceinline__ void g2lds16(const float* g, float* l) {
    __builtin_amdgcn_global_load_lds(
        (const __attribute__((address_space(1))) void*)g,
        (__attribute__((address_space(3))) void*)l, 16, 0, 0);
}

template <int KB>   // k handled per block = I_DIM / KSPLIT
__global__ __launch_bounds__(256, 2) void trop_main(
    const float* __restrict__ x,    // [B_DIM][I_DIM]
    const float* __restrict__ W,    // [O_DIM][I_DIM]
    float* __restrict__ part)       // [KSPLIT][B_DIM][O_DIM]
{
    constexpr int NCH = KB / KT;
    constexpr int NKQ = KT / 4;     // 8 k-quads per chunk
    static_assert(KB % KT == 0, "");
    __shared__ __align__(16) float xs[2][BT * KT];   // 16 KB per buf
    __shared__ __align__(16) float ws[2][OT * KT];

    const int tid  = threadIdx.x;
    const int to   = tid & 15;      // o-fragment selector (0..15)
    const int tb   = tid >> 4;      // b-fragment selector (0..15)
    const int wave = tid >> 6;
    const int lane = tid & 63;
    const int o0 = blockIdx.x * OT;
    const int b0 = blockIdx.y * BT;
    const int kz = blockIdx.z;
    const int kbase = kz * KB;

    // staging geometry: one 1KB DMA covers 8 rows x 8 swizzled k-quads
    const int ro8 = lane >> 3;             // row within 8-row group
    const int q   = (lane & 7) ^ ro8;      // global k-quad held by this slot

    float acc[8][8];
    #pragma unroll
    for (int i = 0; i < 8; ++i)
        #pragma unroll
        for (int j = 0; j < 8; ++j)
            acc[i][j] = -FLT_MAX;

    auto stage = [&](int c, int buf) {
        const int k0 = kbase + c * KT;
        #pragma unroll
        for (int i = 0; i < 4; ++i) {
            const int t = wave * 4 + i;    // wave-uniform LDS base
            g2lds16(&x[(size_t)(b0 + 8 * t + ro8) * I_DIM + k0 + 4 * q],
                    &xs[buf][t * 256]);
        }
        #pragma unroll
        for (int i = 0; i < 4; ++i) {
            const int t = wave * 4 + i;
            g2lds16(&W[(size_t)(o0 + 8 * t + ro8) * I_DIM + k0 + 4 * q],
                    &ws[buf][t * 256]);
        }
    };

    const int swx = tb & 7;   // k-quad swizzle, per-thread-uniform (x rows: tb+16*ii)
    const int swo = to & 7;   // (W rows: to+16*jj)

    auto compute = [&](int buf) {
        const float* xB = &xs[buf][tb * KT];
        const float* wB = &ws[buf][to * KT];

        f32x4 xv[2][8];        // parity banks, cross-kq pipelined
        f32x4 wb2[2];          // 2-deep rotating W buffer

        // chunk prologue: kq=0 fragments
        #pragma unroll
        for (int ii = 0; ii < 8; ++ii)
            xv[0][ii] = *(const f32x4*)&xB[ii * 16 * KT + 4 * swx];      // kq=0 ^ swx
        wb2[0] = *(const f32x4*)&wB[0 * 16 * KT + 4 * swo];
        wb2[1] = *(const f32x4*)&wB[1 * 16 * KT + 4 * swo];

        #pragma unroll
        for (int kq = 0; kq < NKQ; ++kq) {
            const int cur   = kq & 1;
            const int woff  = 4 * (kq ^ swo);
            const int xoffN = 4 * ((kq + 1) ^ swx);
            const int woffN = 4 * ((kq + 1) ^ swo);

            #pragma unroll
            for (int jj = 0; jj < 8; ++jj) {
                const f32x4 wc = wb2[jj & 1];
                if (jj < 6) {
                    wb2[jj & 1] = *(const f32x4*)&wB[(jj + 2) * 16 * KT + woff];
                } else if (kq + 1 < NKQ) {
                    // last two jj slots: prefetch next kq's w0/w1 and x bank
                    wb2[jj & 1] = *(const f32x4*)&wB[(jj - 6) * 16 * KT + woffN];
                    #pragma unroll
                    for (int u = 0; u < 4; ++u)
                        xv[cur ^ 1][4 * (jj - 6) + u] =
                            *(const f32x4*)&xB[(4 * (jj - 6) + u) * 16 * KT + xoffN];
                }
                #pragma unroll
                for (int ii = 0; ii < 8; ++ii) {
                    const f32x4 s = xv[cur][ii] + wc;   // 2x v_pk_add_f32
                    float a = acc[ii][jj];
                    a = fmaxf(a, fmaxf(s.x, s.y));      // v_max3_f32
                    a = fmaxf(a, fmaxf(s.z, s.w));      // v_max3_f32
                    acc[ii][jj] = a;
                }
            }
        }
    };

    stage(0, 0);
    for (int c = 0; c < NCH; ++c) {
        __syncthreads();                              // chunk c staged; prev reads done
        if (c + 1 < NCH) stage(c + 1, (c + 1) & 1);   // DMA overlaps compute
        compute(c & 1);
    }

    // epilogue: private slab, coalesced stores
    float* pout = part + (size_t)kz * (B_DIM * O_DIM);
    #pragma unroll
    for (int ii = 0; ii < 8; ++ii) {
        const int b = b0 + tb + 16 * ii;
        #pragma unroll
        for (int jj = 0; jj < 8; ++jj)
            pout[(size_t)b * O_DIM + o0 + to + 16 * jj] = acc[ii][jj];
    }
}

template <int KS>
__global__ __launch_bounds__(256) void trop_reduce(
    const float* __restrict__ part, float* __restrict__ y)
{
    constexpr int N4 = B_DIM * O_DIM / 4;
    const int idx = blockIdx.x * 256 + threadIdx.x;
    const float4* p = (const float4*)part;
    float4 m = p[idx];
    #pragma unroll
    for (int s = 1; s < KS; ++s) {
        const float4 v = p[(size_t)s * N4 + idx];
        m.x = fmaxf(m.x, v.x); m.y = fmaxf(m.y, v.y);
        m.z = fmaxf(m.z, v.z); m.w = fmaxf(m.w, v.w);
    }
    ((float4*)y)[idx] = m;
}

extern "C" void kernel_launch(void* const* d_in, const int* in_sizes, int n_in,
                              void* d_out, int out_size, void* d_ws, size_t ws_size,
                              hipStream_t stream) {
    const float* x = (const float*)d_in[0];
    const float* W = (const float*)d_in[1];
    float* y = (float*)d_out;
    float* part = (float*)d_ws;
    const size_t slab = (size_t)B_DIM * O_DIM * sizeof(float);   // 2 MB
    const dim3 rgrid(B_DIM * O_DIM / 4 / 256);

    if (ws_size >= 16 * slab) {          // 512 blocks = 2/CU
        trop_main<I_DIM / 16><<<dim3(O_DIM / OT, B_DIM / BT, 16), 256, 0, stream>>>(x, W, part);
        trop_reduce<16><<<rgrid, 256, 0, stream>>>(part, y);
    } else if (ws_size >= 8 * slab) {
        trop_main<I_DIM / 8><<<dim3(O_DIM / OT, B_DIM / BT, 8), 256, 0, stream>>>(x, W, part);
        trop_reduce<8><<<rgrid, 256, 0, stream>>>(part, y);
    } else if (ws_size >= 4 * slab) {
        trop_main<I_DIM / 4><<<dim3(O_DIM / OT, B_DIM / BT, 4), 256, 0, stream>>>(x, W, part);
        trop_reduce<4><<<rgrid, 256, 0, stream>>>(part, y);
    } else if (ws_size >= 2 * slab) {
        trop_main<I_DIM / 2><<<dim3(O_DIM / OT, B_DIM / BT, 2), 256, 0, stream>>>(x, W, part);
        trop_reduce<2><<<rgrid, 256, 0, stream>>>(part, y);
    } else {
        trop_main<I_DIM><<<dim3(O_DIM / OT, B_DIM / BT, 1), 256, 0, stream>>>(x, W, y);
    }
}